// Round 1
// baseline (80.536 us; speedup 1.0000x reference)
//
#include <hip/hip_runtime.h>
#include <hip/hip_bf16.h>

typedef __attribute__((ext_vector_type(8))) short bf16x8;
typedef __attribute__((ext_vector_type(4))) float f32x4;
typedef unsigned short u16;
typedef unsigned int u32;

#define EMB 128
#define HEADS 8
#define HD 16
#define NB 2
#define NN 128
#define SEQ (NB*NN)      // 256 independent attention rows
#define NTOK (SEQ*NN)    // 32768 tokens

// round-to-nearest-even fp32 -> bf16
static __device__ __forceinline__ u16 f2bf(float f) {
    union { float f; u32 u; } v; v.f = f;
    u32 u = v.u;
    return (u16)((u + 0x7FFFu + ((u >> 16) & 1u)) >> 16);
}

// ---------------------------------------------------------------------------
// Weight prep: wt[mat][n][k] = bf16(w[mat][k][n])  (transpose + convert), mat: q,k,v,o
__global__ void __launch_bounds__(256) k_prep(const float* __restrict__ wq,
        const float* __restrict__ wk, const float* __restrict__ wv,
        const float* __restrict__ wo, u16* __restrict__ wt) {
    int i = blockIdx.x * 256 + threadIdx.x;      // 0..65535
    int mat = i >> 14, rem = i & 16383;
    int k = rem >> 7, n = rem & 127;
    const float* src = mat == 0 ? wq : mat == 1 ? wk : mat == 2 ? wv : wo;
    wt[mat * 16384 + n * 128 + k] = f2bf(src[rem]);
}

// ---------------------------------------------------------------------------
// LayerNorm: 64 tokens/block, 4 threads/token, output bf16 X[t][c]
__global__ void __launch_bounds__(256) k_ln(const float* __restrict__ pe,
        const float* __restrict__ g, const float* __restrict__ bia,
        u16* __restrict__ X) {
    int tid = threadIdx.x;
    int t = blockIdx.x * 64 + (tid >> 2);
    int q = tid & 3;
    const float4* src = reinterpret_cast<const float4*>(pe + (size_t)t * EMB);
    float4 v[8];
    float s = 0.f, ss = 0.f;
#pragma unroll
    for (int i = 0; i < 8; ++i) {
        v[i] = src[i * 4 + q];   // cols i*16 + q*4 .. +3
        s += v[i].x + v[i].y + v[i].z + v[i].w;
        ss += v[i].x * v[i].x + v[i].y * v[i].y + v[i].z * v[i].z + v[i].w * v[i].w;
    }
    s += __shfl_xor(s, 1); ss += __shfl_xor(ss, 1);
    s += __shfl_xor(s, 2); ss += __shfl_xor(ss, 2);
    float mean = s * (1.f / EMB);
    float var = ss * (1.f / EMB) - mean * mean;
    float rstd = rsqrtf(var + 1e-5f);
#pragma unroll
    for (int i = 0; i < 8; ++i) {
        int c = i * 16 + q * 4;
        float4 gg = *reinterpret_cast<const float4*>(g + c);
        float4 bb = *reinterpret_cast<const float4*>(bia + c);
        u16 r0 = f2bf((v[i].x - mean) * rstd * gg.x + bb.x);
        u16 r1 = f2bf((v[i].y - mean) * rstd * gg.y + bb.y);
        u16 r2 = f2bf((v[i].z - mean) * rstd * gg.z + bb.z);
        u16 r3 = f2bf((v[i].w - mean) * rstd * gg.w + bb.w);
        uint2 packed;
        packed.x = (u32)r0 | ((u32)r1 << 16);
        packed.y = (u32)r2 | ((u32)r3 << 16);
        *reinterpret_cast<uint2*>(X + (size_t)t * EMB + c) = packed;
    }
}

// ---------------------------------------------------------------------------
// QKV GEMM: C[64 x 128] = Xtile @ W(which) (+bias, q*0.25). which: 0=q,1=k,2=v
// Q/K layout: [seq][h][tok][d]; V stored transposed: [seq][h][d][tok]
__global__ void __launch_bounds__(256) k_qkv(const u16* __restrict__ X,
        const u16* __restrict__ wt,
        const float* __restrict__ bq, const float* __restrict__ bk,
        const float* __restrict__ bv,
        u16* __restrict__ Q, u16* __restrict__ Kb, u16* __restrict__ Vt) {
    __shared__ u16 Xs[64 * 136];   // row pad: 17 granules of 16B
    __shared__ u16 Ws[128 * 136];
    int tid = threadIdx.x;
    int m0 = blockIdx.x * 64;
    int which = blockIdx.y;
    {
        const uint4* xg = reinterpret_cast<const uint4*>(X + (size_t)m0 * EMB);
        uint4* xs = reinterpret_cast<uint4*>(Xs);
        for (int i = tid; i < 1024; i += 256) xs[(i >> 4) * 17 + (i & 15)] = xg[i];
        const uint4* wg = reinterpret_cast<const uint4*>(wt + which * 16384);
        uint4* wsp = reinterpret_cast<uint4*>(Ws);
        for (int i = tid; i < 2048; i += 256) wsp[(i >> 4) * 17 + (i & 15)] = wg[i];
    }
    __syncthreads();
    int lane = tid & 63, wave = tid >> 6;
    int lo = lane & 15, hi = lane >> 4;
    f32x4 acc[8];
#pragma unroll
    for (int c = 0; c < 8; ++c) acc[c] = f32x4{0.f, 0.f, 0.f, 0.f};
#pragma unroll
    for (int kk = 0; kk < 4; ++kk) {
        bf16x8 a = *reinterpret_cast<const bf16x8*>(&Xs[(wave * 16 + lo) * 136 + kk * 32 + hi * 8]);
#pragma unroll
        for (int c = 0; c < 8; ++c) {
            bf16x8 b = *reinterpret_cast<const bf16x8*>(&Ws[(c * 16 + lo) * 136 + kk * 32 + hi * 8]);
            acc[c] = __builtin_amdgcn_mfma_f32_16x16x32_bf16(a, b, acc[c], 0, 0, 0);
        }
    }
    const float* bias = which == 0 ? bq : which == 1 ? bk : bv;
#pragma unroll
    for (int c = 0; c < 8; ++c) {
        int col = c * 16 + lo;      // h = c, d = lo
        float bval = bias[col];
        if (which < 2) {
            u16* dst = which == 0 ? Q : Kb;
#pragma unroll
            for (int j = 0; j < 4; ++j) {
                int t = m0 + wave * 16 + hi * 4 + j;
                float vvv = acc[c][j] + bval;
                if (which == 0) vvv *= 0.25f;   // 1/sqrt(16)
                dst[(size_t)(t >> 7) * 16384 + c * 2048 + (t & 127) * 16 + lo] = f2bf(vvv);
            }
        } else {
            int t0 = m0 + wave * 16 + hi * 4;
            u16 r0 = f2bf(acc[c][0] + bval);
            u16 r1 = f2bf(acc[c][1] + bval);
            u16 r2 = f2bf(acc[c][2] + bval);
            u16 r3 = f2bf(acc[c][3] + bval);
            uint2 packed;
            packed.x = (u32)r0 | ((u32)r1 << 16);
            packed.y = (u32)r2 | ((u32)r3 << 16);
            *reinterpret_cast<uint2*>(&Vt[(size_t)(t0 >> 7) * 16384 + c * 2048 + lo * 128 + (t0 & 127)]) = packed;
        }
    }
}

// ---------------------------------------------------------------------------
// Attention: one wave per (seq, head). S=128x128 (K=16, zero-padded to 32),
// softmax in fp32, P@V with K=128. ctx[t][h*16+d] bf16.
__global__ void __launch_bounds__(64) k_attn(const u16* __restrict__ Q,
        const u16* __restrict__ Kb, const u16* __restrict__ Vt,
        u16* __restrict__ ctx) {
    __shared__ u16 Qs[128 * 24];   // [tok][16 d], pad to 24
    __shared__ u16 Ks[128 * 24];
    __shared__ u16 Vs[16 * 136];   // [d][128 tok], pad to 136
    __shared__ u16 Ps[16 * 136];   // [qrow 16][128 key], pad to 136
    int lane = threadIdx.x;
    int seq = blockIdx.x >> 3, h = blockIdx.x & 7;
    size_t base = (size_t)seq * 16384 + h * 2048;
    {
        const uint4* qg = reinterpret_cast<const uint4*>(Q + base);
        const uint4* kg = reinterpret_cast<const uint4*>(Kb + base);
        const uint4* vg = reinterpret_cast<const uint4*>(Vt + base);
        uint4* qs = reinterpret_cast<uint4*>(Qs);
        uint4* ks = reinterpret_cast<uint4*>(Ks);
        uint4* vs = reinterpret_cast<uint4*>(Vs);
        for (int i = lane; i < 256; i += 64) {
            qs[(i >> 1) * 3 + (i & 1)] = qg[i];
            ks[(i >> 1) * 3 + (i & 1)] = kg[i];
            vs[(i >> 4) * 17 + (i & 15)] = vg[i];
        }
    }
    __syncthreads();
    int lo = lane & 15, hi = lane >> 4;
    for (int qt = 0; qt < 8; ++qt) {
        // S tile row: q rows [qt*16, qt*16+16) x all 128 keys
        bf16x8 a{};
        if (lane < 32) a = *reinterpret_cast<const bf16x8*>(&Qs[(qt * 16 + lo) * 24 + hi * 8]);
        f32x4 s[8];
#pragma unroll
        for (int c = 0; c < 8; ++c) {
            bf16x8 b{};
            if (lane < 32) b = *reinterpret_cast<const bf16x8*>(&Ks[(c * 16 + lo) * 24 + hi * 8]);
            s[c] = __builtin_amdgcn_mfma_f32_16x16x32_bf16(a, b, f32x4{0.f, 0.f, 0.f, 0.f}, 0, 0, 0);
        }
        __syncthreads();   // WAR: prev iteration's PV reads of Ps done before rewrite
        // softmax over keys; lane holds rows 4*hi+j at col c*16+lo
#pragma unroll
        for (int j = 0; j < 4; ++j) {
            float m = s[0][j];
#pragma unroll
            for (int c = 1; c < 8; ++c) m = fmaxf(m, s[c][j]);
            m = fmaxf(m, __shfl_xor(m, 1));
            m = fmaxf(m, __shfl_xor(m, 2));
            m = fmaxf(m, __shfl_xor(m, 4));
            m = fmaxf(m, __shfl_xor(m, 8));
            float sum = 0.f;
#pragma unroll
            for (int c = 0; c < 8; ++c) { float p = __expf(s[c][j] - m); s[c][j] = p; sum += p; }
            sum += __shfl_xor(sum, 1);
            sum += __shfl_xor(sum, 2);
            sum += __shfl_xor(sum, 4);
            sum += __shfl_xor(sum, 8);
            float inv = 1.f / sum;
#pragma unroll
            for (int c = 0; c < 8; ++c)
                Ps[(hi * 4 + j) * 136 + c * 16 + lo] = f2bf(s[c][j] * inv);
        }
        __syncthreads();
        // O[16 x 16] = P[16 x 128] @ V[128 x 16] : 4 MFMAs over K
        f32x4 o = f32x4{0.f, 0.f, 0.f, 0.f};
#pragma unroll
        for (int kk = 0; kk < 4; ++kk) {
            bf16x8 pa = *reinterpret_cast<const bf16x8*>(&Ps[lo * 136 + kk * 32 + hi * 8]);
            bf16x8 vb = *reinterpret_cast<const bf16x8*>(&Vs[lo * 136 + kk * 32 + hi * 8]);
            o = __builtin_amdgcn_mfma_f32_16x16x32_bf16(pa, vb, o, 0, 0, 0);
        }
#pragma unroll
        for (int j = 0; j < 4; ++j) {
            int t = seq * 128 + qt * 16 + hi * 4 + j;
            ctx[(size_t)t * EMB + h * 16 + lo] = f2bf(o[j]);
        }
    }
}

// ---------------------------------------------------------------------------
// Output projection: out[t][c] = (ctx @ wo + bo) * mask[t], fp32 out
__global__ void __launch_bounds__(256) k_out(const u16* __restrict__ ctx,
        const u16* __restrict__ wt, const float* __restrict__ bo,
        const float* __restrict__ mask, float* __restrict__ out) {
    __shared__ u16 Cs[64 * 136];
    __shared__ u16 Ws[128 * 136];
    int tid = threadIdx.x;
    int m0 = blockIdx.x * 64;
    {
        const uint4* cg = reinterpret_cast<const uint4*>(ctx + (size_t)m0 * EMB);
        uint4* cs = reinterpret_cast<uint4*>(Cs);
        for (int i = tid; i < 1024; i += 256) cs[(i >> 4) * 17 + (i & 15)] = cg[i];
        const uint4* wg = reinterpret_cast<const uint4*>(wt + 3 * 16384);
        uint4* wsp = reinterpret_cast<uint4*>(Ws);
        for (int i = tid; i < 2048; i += 256) wsp[(i >> 4) * 17 + (i & 15)] = wg[i];
    }
    __syncthreads();
    int lane = tid & 63, wave = tid >> 6;
    int lo = lane & 15, hi = lane >> 4;
    f32x4 acc[8];
#pragma unroll
    for (int c = 0; c < 8; ++c) acc[c] = f32x4{0.f, 0.f, 0.f, 0.f};
#pragma unroll
    for (int kk = 0; kk < 4; ++kk) {
        bf16x8 a = *reinterpret_cast<const bf16x8*>(&Cs[(wave * 16 + lo) * 136 + kk * 32 + hi * 8]);
#pragma unroll
        for (int c = 0; c < 8; ++c) {
            bf16x8 b = *reinterpret_cast<const bf16x8*>(&Ws[(c * 16 + lo) * 136 + kk * 32 + hi * 8]);
            acc[c] = __builtin_amdgcn_mfma_f32_16x16x32_bf16(a, b, acc[c], 0, 0, 0);
        }
    }
#pragma unroll
    for (int c = 0; c < 8; ++c) {
        int col = c * 16 + lo;
        float bval = bo[col];
#pragma unroll
        for (int j = 0; j < 4; ++j) {
            int t = m0 + wave * 16 + hi * 4 + j;
            out[(size_t)t * EMB + col] = (acc[c][j] + bval) * mask[t];
        }
    }
}

// ---------------------------------------------------------------------------
extern "C" void kernel_launch(void* const* d_in, const int* in_sizes, int n_in,
                              void* d_out, int out_size, void* d_ws, size_t ws_size,
                              hipStream_t stream) {
    const float* pe   = (const float*)d_in[0];
    const float* mask = (const float*)d_in[1];
    const float* ln_g = (const float*)d_in[2];
    const float* ln_b = (const float*)d_in[3];
    const float* wq   = (const float*)d_in[4];
    const float* bq   = (const float*)d_in[5];
    const float* wk   = (const float*)d_in[6];
    const float* bk   = (const float*)d_in[7];
    const float* wv   = (const float*)d_in[8];
    const float* bv   = (const float*)d_in[9];
    const float* wo   = (const float*)d_in[10];
    const float* bo   = (const float*)d_in[11];
    float* out = (float*)d_out;

    u16* W   = (u16*)d_ws;
    u16* X   = W;                    // 32768*128 bf16 = 8 MB
    u16* Q   = W + 4194304;          // [seq][h][tok][d]
    u16* Kb  = W + 8388608;
    u16* Vt  = W + 12582912;         // [seq][h][d][tok]
    u16* ctx = W + 16777216;         // [t][EMB]
    u16* wt  = W + 20971520;         // 4 x [n][k] bf16

    hipLaunchKernelGGL(k_prep, dim3(256), dim3(256), 0, stream, wq, wk, wv, wo, wt);
    hipLaunchKernelGGL(k_ln,   dim3(512), dim3(256), 0, stream, pe, ln_g, ln_b, X);
    hipLaunchKernelGGL(k_qkv,  dim3(512, 3), dim3(256), 0, stream, X, wt, bq, bk, bv, Q, Kb, Vt);
    hipLaunchKernelGGL(k_attn, dim3(2048), dim3(64), 0, stream, Q, Kb, Vt, ctx);
    hipLaunchKernelGGL(k_out,  dim3(512), dim3(256), 0, stream, ctx, wt, bo, mask, out);
}

// Round 2
// 60.131 us; speedup vs baseline: 1.3393x; 1.3393x over previous
//
#include <hip/hip_runtime.h>
#include <hip/hip_bf16.h>

typedef __attribute__((ext_vector_type(8))) short bf16x8;
typedef __attribute__((ext_vector_type(4))) float f32x4;
typedef __attribute__((ext_vector_type(16))) float f32x16;
typedef __attribute__((ext_vector_type(2))) unsigned int u32x2;
typedef unsigned short u16;
typedef unsigned int u32;

#define EMB 128
#define HEADS 8
#define HD 16
#define NB 2
#define NN 128
#define SEQ (NB*NN)      // 256 independent attention rows
#define NTOK (SEQ*NN)    // 32768 tokens

// round-to-nearest-even fp32 -> bf16
static __device__ __forceinline__ u16 f2bf(float f) {
    union { float f; u32 u; } v; v.f = f;
    u32 u = v.u;
    return (u16)((u + 0x7FFFu + ((u >> 16) & 1u)) >> 16);
}

// packed fp32 pair -> bf16x2 in one u32 (low = a, high = b)
static __device__ __forceinline__ u32 cvtpk(float a, float b) {
    u32 r;
    asm("v_cvt_pk_bf16_f32 %0, %1, %2" : "=v"(r) : "v"(a), "v"(b));
    return r;
}

// exchange: a' = [a.lo32 | b.lo32(partner)], b' = [a.hi32(partner) | b.hi32]
static __device__ __forceinline__ void plswap(u32& a, u32& b) {
#if __has_builtin(__builtin_amdgcn_permlane32_swap)
    u32x2 r = __builtin_amdgcn_permlane32_swap(a, b, false, false);
    a = r[0]; b = r[1];
#else
    u32 sa = __shfl_xor(a, 32), sb = __shfl_xor(b, 32);
    bool hi = (threadIdx.x & 32) != 0;
    u32 na = hi ? sb : a;
    u32 nb = hi ? b : sa;
    a = na; b = nb;
#endif
}

// ---------------------------------------------------------------------------
// Weight prep: wt[mat][n][k] = bf16(w[mat][k][n])  (transpose + convert), mat: q,k,v,o
__global__ void __launch_bounds__(256) k_prep(const float* __restrict__ wq,
        const float* __restrict__ wk, const float* __restrict__ wv,
        const float* __restrict__ wo, u16* __restrict__ wt) {
    int i = blockIdx.x * 256 + threadIdx.x;      // 0..65535
    int mat = i >> 14, rem = i & 16383;
    int k = rem >> 7, n = rem & 127;
    const float* src = mat == 0 ? wq : mat == 1 ? wk : mat == 2 ? wv : wo;
    wt[mat * 16384 + n * 128 + k] = f2bf(src[rem]);
}

// ---------------------------------------------------------------------------
// LayerNorm: 64 tokens/block, 4 threads/token, output bf16 X[t][c]
__global__ void __launch_bounds__(256) k_ln(const float* __restrict__ pe,
        const float* __restrict__ g, const float* __restrict__ bia,
        u16* __restrict__ X) {
    int tid = threadIdx.x;
    int t = blockIdx.x * 64 + (tid >> 2);
    int q = tid & 3;
    const float4* src = reinterpret_cast<const float4*>(pe + (size_t)t * EMB);
    float4 v[8];
    float s = 0.f, ss = 0.f;
#pragma unroll
    for (int i = 0; i < 8; ++i) {
        v[i] = src[i * 4 + q];   // cols i*16 + q*4 .. +3
        s += v[i].x + v[i].y + v[i].z + v[i].w;
        ss += v[i].x * v[i].x + v[i].y * v[i].y + v[i].z * v[i].z + v[i].w * v[i].w;
    }
    s += __shfl_xor(s, 1); ss += __shfl_xor(ss, 1);
    s += __shfl_xor(s, 2); ss += __shfl_xor(ss, 2);
    float mean = s * (1.f / EMB);
    float var = ss * (1.f / EMB) - mean * mean;
    float rstd = rsqrtf(var + 1e-5f);
#pragma unroll
    for (int i = 0; i < 8; ++i) {
        int c = i * 16 + q * 4;
        float4 gg = *reinterpret_cast<const float4*>(g + c);
        float4 bb = *reinterpret_cast<const float4*>(bia + c);
        u16 r0 = f2bf((v[i].x - mean) * rstd * gg.x + bb.x);
        u16 r1 = f2bf((v[i].y - mean) * rstd * gg.y + bb.y);
        u16 r2 = f2bf((v[i].z - mean) * rstd * gg.z + bb.z);
        u16 r3 = f2bf((v[i].w - mean) * rstd * gg.w + bb.w);
        uint2 packed;
        packed.x = (u32)r0 | ((u32)r1 << 16);
        packed.y = (u32)r2 | ((u32)r3 << 16);
        *reinterpret_cast<uint2*>(X + (size_t)t * EMB + c) = packed;
    }
}

// ---------------------------------------------------------------------------
// QKV GEMM: C[64 x 128] = Xtile @ W(which) (+bias, q*0.25). which: 0=q,1=k,2=v
// Q/K layout: [seq][h][tok][d]; V stored transposed: [seq][h][d][tok]
__global__ void __launch_bounds__(256) k_qkv(const u16* __restrict__ X,
        const u16* __restrict__ wt,
        const float* __restrict__ bq, const float* __restrict__ bk,
        const float* __restrict__ bv,
        u16* __restrict__ Q, u16* __restrict__ Kb, u16* __restrict__ Vt) {
    __shared__ u16 Xs[64 * 136];   // row pad: 17 granules of 16B
    __shared__ u16 Ws[128 * 136];
    int tid = threadIdx.x;
    int m0 = blockIdx.x * 64;
    int which = blockIdx.y;
    {
        const uint4* xg = reinterpret_cast<const uint4*>(X + (size_t)m0 * EMB);
        uint4* xs = reinterpret_cast<uint4*>(Xs);
        for (int i = tid; i < 1024; i += 256) xs[(i >> 4) * 17 + (i & 15)] = xg[i];
        const uint4* wg = reinterpret_cast<const uint4*>(wt + which * 16384);
        uint4* wsp = reinterpret_cast<uint4*>(Ws);
        for (int i = tid; i < 2048; i += 256) wsp[(i >> 4) * 17 + (i & 15)] = wg[i];
    }
    __syncthreads();
    int lane = tid & 63, wave = tid >> 6;
    int lo = lane & 15, hi = lane >> 4;
    f32x4 acc[8];
#pragma unroll
    for (int c = 0; c < 8; ++c) acc[c] = f32x4{0.f, 0.f, 0.f, 0.f};
#pragma unroll
    for (int kk = 0; kk < 4; ++kk) {
        bf16x8 a = *reinterpret_cast<const bf16x8*>(&Xs[(wave * 16 + lo) * 136 + kk * 32 + hi * 8]);
#pragma unroll
        for (int c = 0; c < 8; ++c) {
            bf16x8 b = *reinterpret_cast<const bf16x8*>(&Ws[(c * 16 + lo) * 136 + kk * 32 + hi * 8]);
            acc[c] = __builtin_amdgcn_mfma_f32_16x16x32_bf16(a, b, acc[c], 0, 0, 0);
        }
    }
    const float* bias = which == 0 ? bq : which == 1 ? bk : bv;
#pragma unroll
    for (int c = 0; c < 8; ++c) {
        int col = c * 16 + lo;      // h = c, d = lo
        float bval = bias[col];
        if (which < 2) {
            u16* dst = which == 0 ? Q : Kb;
#pragma unroll
            for (int j = 0; j < 4; ++j) {
                int t = m0 + wave * 16 + hi * 4 + j;
                float vvv = acc[c][j] + bval;
                if (which == 0) vvv *= 0.25f;   // 1/sqrt(16)
                dst[(size_t)(t >> 7) * 16384 + c * 2048 + (t & 127) * 16 + lo] = f2bf(vvv);
            }
        } else {
            int t0 = m0 + wave * 16 + hi * 4;
            u16 r0 = f2bf(acc[c][0] + bval);
            u16 r1 = f2bf(acc[c][1] + bval);
            u16 r2 = f2bf(acc[c][2] + bval);
            u16 r3 = f2bf(acc[c][3] + bval);
            uint2 packed;
            packed.x = (u32)r0 | ((u32)r1 << 16);
            packed.y = (u32)r2 | ((u32)r3 << 16);
            *reinterpret_cast<uint2*>(&Vt[(size_t)(t0 >> 7) * 16384 + c * 2048 + lo * 128 + (t0 & 127)]) = packed;
        }
    }
}

// ---------------------------------------------------------------------------
// Attention v2: one wave per (seq, head, 32-q-row tile). Zero LDS, zero barriers.
// QK^T swapped: S^T tile = mfma_32x32x16(K_tile, Q_tile) -> lane owns
// S[q=lane&31][64 of 128 k] in regs. Softmax per-lane + one shfl_xor(32).
// PV: O^T = V^T @ P^T via 8 k-chunks; P^T B-frags built in-register with
// cvt_pk_bf16 + permlane32_swap; V^T A-frags are contiguous 16B global loads
// from Vt (L1-resident). Output regs 0..7 give d = (r&3)+8*(r>>2)+4*hi.
__global__ void __launch_bounds__(64) k_attn(const u16* __restrict__ Q,
        const u16* __restrict__ Kb, const u16* __restrict__ Vt,
        u16* __restrict__ ctx) {
    int lane = threadIdx.x;
    int bx = blockIdx.x;
    int qt = bx & 3, h = (bx >> 2) & 7, seq = bx >> 5;
    int lo = lane & 31, hi = lane >> 5;
    size_t base = (size_t)seq * 16384 + (size_t)h * 2048;

    // Q fragment (B operand): col=q=lo, k(=d) = hi*8 + e
    bf16x8 qf = *reinterpret_cast<const bf16x8*>(Q + base + (size_t)(qt * 32 + lo) * 16 + hi * 8);

    // QK^T: 4 tiles of 32 keys, K=16 (= head dim, no padding)
    f32x16 s[4];
    const f32x16 zero = {};
#pragma unroll
    for (int t = 0; t < 4; ++t) {
        bf16x8 kf = *reinterpret_cast<const bf16x8*>(Kb + base + (size_t)(t * 32 + lo) * 16 + hi * 8);
        s[t] = __builtin_amdgcn_mfma_f32_32x32x16_bf16(kf, qf, zero, 0, 0, 0);
    }

    // softmax over k (each lane holds 64 of 128 k for its q; partner lane^32 has rest)
    float m = s[0][0];
#pragma unroll
    for (int t = 0; t < 4; ++t)
#pragma unroll
        for (int r = 0; r < 16; ++r) m = fmaxf(m, s[t][r]);
    m = fmaxf(m, __shfl_xor(m, 32));
    float sum = 0.f;
#pragma unroll
    for (int t = 0; t < 4; ++t)
#pragma unroll
        for (int r = 0; r < 16; ++r) {
            float p = __expf(s[t][r] - m);
            s[t][r] = p;
            sum += p;
        }
    sum += __shfl_xor(sum, 32);
    float inv = 1.f / sum;

    // PV: O^T = V^T @ P^T, 8 chunks of 16 k
    f32x16 o = {};
#pragma unroll
    for (int c = 0; c < 8; ++c) {
        int t = c >> 1, hf = (c & 1) * 8;
        u32 x0 = cvtpk(s[t][hf + 0], s[t][hf + 1]);
        u32 x1 = cvtpk(s[t][hf + 2], s[t][hf + 3]);
        u32 y0 = cvtpk(s[t][hf + 4], s[t][hf + 5]);
        u32 y1 = cvtpk(s[t][hf + 6], s[t][hf + 7]);
        plswap(x0, y0);   // x0 -> w0 (k hi*8+0..1), y0 -> w2 (k hi*8+4..5)
        plswap(x1, y1);   // x1 -> w1 (k hi*8+2..3), y1 -> w3 (k hi*8+6..7)
        union { u32 w[4]; bf16x8 v; } pb;
        pb.w[0] = x0; pb.w[1] = x1; pb.w[2] = y0; pb.w[3] = y1;
        // V^T A-frag: row=d=lo&15 (lanes 16..31 duplicate -> dup output regs 8..15, ignored)
        bf16x8 va = *reinterpret_cast<const bf16x8*>(Vt + base + (size_t)(lo & 15) * 128 + c * 16 + hi * 8);
        o = __builtin_amdgcn_mfma_f32_32x32x16_bf16(va, pb.v, o, 0, 0, 0);
    }

    // epilogue: lane holds O[q=lo][d = (r&3)+8*(r>>2)+4*hi] for r=0..7
    int qrow = seq * 128 + qt * 32 + lo;
    u16* dst = ctx + (size_t)qrow * EMB + h * 16;
    uint2 p0, p1;
    p0.x = (u32)f2bf(o[0] * inv) | ((u32)f2bf(o[1] * inv) << 16);
    p0.y = (u32)f2bf(o[2] * inv) | ((u32)f2bf(o[3] * inv) << 16);
    p1.x = (u32)f2bf(o[4] * inv) | ((u32)f2bf(o[5] * inv) << 16);
    p1.y = (u32)f2bf(o[6] * inv) | ((u32)f2bf(o[7] * inv) << 16);
    *reinterpret_cast<uint2*>(dst + 4 * hi) = p0;       // d = 4hi + 0..3
    *reinterpret_cast<uint2*>(dst + 8 + 4 * hi) = p1;   // d = 8 + 4hi + 0..3
}

// ---------------------------------------------------------------------------
// Output projection: out[t][c] = (ctx @ wo + bo) * mask[t], fp32 out
__global__ void __launch_bounds__(256) k_out(const u16* __restrict__ ctx,
        const u16* __restrict__ wt, const float* __restrict__ bo,
        const float* __restrict__ mask, float* __restrict__ out) {
    __shared__ u16 Cs[64 * 136];
    __shared__ u16 Ws[128 * 136];
    int tid = threadIdx.x;
    int m0 = blockIdx.x * 64;
    {
        const uint4* cg = reinterpret_cast<const uint4*>(ctx + (size_t)m0 * EMB);
        uint4* cs = reinterpret_cast<uint4*>(Cs);
        for (int i = tid; i < 1024; i += 256) cs[(i >> 4) * 17 + (i & 15)] = cg[i];
        const uint4* wg = reinterpret_cast<const uint4*>(wt + 3 * 16384);
        uint4* wsp = reinterpret_cast<uint4*>(Ws);
        for (int i = tid; i < 2048; i += 256) wsp[(i >> 4) * 17 + (i & 15)] = wg[i];
    }
    __syncthreads();
    int lane = tid & 63, wave = tid >> 6;
    int lo = lane & 15, hi = lane >> 4;
    f32x4 acc[8];
#pragma unroll
    for (int c = 0; c < 8; ++c) acc[c] = f32x4{0.f, 0.f, 0.f, 0.f};
#pragma unroll
    for (int kk = 0; kk < 4; ++kk) {
        bf16x8 a = *reinterpret_cast<const bf16x8*>(&Cs[(wave * 16 + lo) * 136 + kk * 32 + hi * 8]);
#pragma unroll
        for (int c = 0; c < 8; ++c) {
            bf16x8 b = *reinterpret_cast<const bf16x8*>(&Ws[(c * 16 + lo) * 136 + kk * 32 + hi * 8]);
            acc[c] = __builtin_amdgcn_mfma_f32_16x16x32_bf16(a, b, acc[c], 0, 0, 0);
        }
    }
#pragma unroll
    for (int c = 0; c < 8; ++c) {
        int col = c * 16 + lo;
        float bval = bo[col];
#pragma unroll
        for (int j = 0; j < 4; ++j) {
            int t = m0 + wave * 16 + hi * 4 + j;
            out[(size_t)t * EMB + col] = (acc[c][j] + bval) * mask[t];
        }
    }
}

// ---------------------------------------------------------------------------
extern "C" void kernel_launch(void* const* d_in, const int* in_sizes, int n_in,
                              void* d_out, int out_size, void* d_ws, size_t ws_size,
                              hipStream_t stream) {
    const float* pe   = (const float*)d_in[0];
    const float* mask = (const float*)d_in[1];
    const float* ln_g = (const float*)d_in[2];
    const float* ln_b = (const float*)d_in[3];
    const float* wq   = (const float*)d_in[4];
    const float* bq   = (const float*)d_in[5];
    const float* wk   = (const float*)d_in[6];
    const float* bk   = (const float*)d_in[7];
    const float* wv   = (const float*)d_in[8];
    const float* bv   = (const float*)d_in[9];
    const float* wo   = (const float*)d_in[10];
    const float* bo   = (const float*)d_in[11];
    float* out = (float*)d_out;

    u16* W   = (u16*)d_ws;
    u16* X   = W;                    // 32768*128 bf16 = 8 MB
    u16* Q   = W + 4194304;          // [seq][h][tok][d]
    u16* Kb  = W + 8388608;
    u16* Vt  = W + 12582912;         // [seq][h][d][tok]
    u16* ctx = W + 16777216;         // [t][EMB]
    u16* wt  = W + 20971520;         // 4 x [n][k] bf16

    hipLaunchKernelGGL(k_prep, dim3(256), dim3(256), 0, stream, wq, wk, wv, wo, wt);
    hipLaunchKernelGGL(k_ln,   dim3(512), dim3(256), 0, stream, pe, ln_g, ln_b, X);
    hipLaunchKernelGGL(k_qkv,  dim3(512, 3), dim3(256), 0, stream, X, wt, bq, bk, bv, Q, Kb, Vt);
    hipLaunchKernelGGL(k_attn, dim3(8192), dim3(64), 0, stream, Q, Kb, Vt, ctx);
    hipLaunchKernelGGL(k_out,  dim3(512), dim3(256), 0, stream, ctx, wt, bo, mask, out);
}